// Round 21
// baseline (492.393 us; speedup 1.0000x reference)
//
#include <hip/hip_runtime.h>
#include <hip/hip_bf16.h>
#include <math.h>

#define NF 64
#define NH 8
#define SLOPE 0.2f

typedef __hip_bfloat16 bf16;
typedef short short8 __attribute__((ext_vector_type(8)));
typedef unsigned int uint4v __attribute__((ext_vector_type(4)));
typedef float f32x4 __attribute__((ext_vector_type(4)));
typedef float f32x2 __attribute__((ext_vector_type(2)));

__device__ __forceinline__ float us2f(unsigned short u){
  union{ unsigned int i; float f; } c; c.i = ((unsigned int)u) << 16; return c.f;
}
// unpack packed 2xbf16 dword -> f32 (low / high element)
__device__ __forceinline__ float lo16(unsigned int u){
  union{ unsigned int i; float f; } c; c.i = u << 16; return c.f;
}
__device__ __forceinline__ float hi16(unsigned int u){
  union{ unsigned int i; float f; } c; c.i = u & 0xFFFF0000u; return c.f;
}
// round-to-nearest-even f32 -> bf16 bits
__device__ __forceinline__ unsigned short f2b_rne(float v){
  union{ float f; unsigned int i; } c; c.f = v;
  unsigned int b = c.i + 0x7FFF + ((c.i >> 16) & 1);
  return (unsigned short)(b >> 16);
}
__device__ __forceinline__ f32x4 mfma16(short8 a, short8 b, f32x4 c){
  return __builtin_amdgcn_mfma_f32_16x16x32_bf16(a, b, c, 0, 0, 0);
}

// ---------- merged weight pre-pack (one dispatch; ranges: prep1|prep2|prep3|prep4) ----------
// Also zeroes gtot (the scan base counter) each launch: runs before k_scan in stream order.
__global__ void __launch_bounds__(64)
k_prep_all(const float* __restrict__ Watt, const float* __restrict__ aatt,
           const float* __restrict__ Wout, const float* __restrict__ aout,
           const float* __restrict__ W1, const float* __restrict__ W2,
           short* __restrict__ Bp1, short* __restrict__ Bp2,
           short* __restrict__ Bp3, short* __restrict__ Bp4,
           int* __restrict__ gtot){
  int b = blockIdx.x;
  int lane = threadIdx.x;
  int kg = lane >> 4, cl = lane & 15;
  if (b == 0 && lane == 0) *gtot = 0;
  if (b < 66){
    int f = b >> 1, ks = b & 1;
    int col = f * 16 + cl;
    for (int j = 0; j < 8; j++){
      int k = ks * 32 + kg * 8 + j;
      float val;
      if (col < 512){
        val = Watt[(size_t)(col >> 6) * 4096 + k * 64 + (col & 63)];
      } else {
        int h = (col - 512) & 7;
        const float* arow = aatt + h * 128 + ((col >= 520) ? 64 : 0);
        const float* wrow = Watt + (size_t)h * 4096 + k * 64;
        float s = 0.f;
        for (int d = 0; d < 64; d++) s += wrow[d] * arow[d];
        val = s;
      }
      unsigned short hu = f2b_rne(val);
      float lof = val - us2f(hu);
      Bp1[((size_t)(ks * 33) + f) * 512 + lane * 8 + j]       = (short)hu;
      Bp1[((size_t)((2 + ks) * 33) + f) * 512 + lane * 8 + j] = (short)f2b_rne(lof);
    }
  } else if (b < 146){
    int bb = b - 66;
    int f = bb >> 4, ks = bb & 15;
    int col = f * 16 + cl;
    for (int j = 0; j < 8; j++){
      int k = ks * 32 + kg * 8 + j;
      float val = 0.f;
      if (col < 64){
        val = Wout[(size_t)k * 64 + col];
      } else if (col == 64 || col == 65){
        const float* arow = aout + ((col == 65) ? 64 : 0);
        const float* wrow = Wout + (size_t)k * 64;
        float s = 0.f;
        for (int d = 0; d < 64; d++) s += wrow[d] * arow[d];
        val = s;
      }
      unsigned short hu = f2b_rne(val);
      float lof = val - us2f(hu);
      Bp2[((size_t)(ks * 5) + f) * 512 + lane * 8 + j]        = (short)hu;
      Bp2[((size_t)((16 + ks) * 5) + f) * 512 + lane * 8 + j] = (short)f2b_rne(lof);
    }
  } else if (b < 226){
    int bb = b - 146;
    int f = bb >> 1, ks = bb & 1;
    int col = f * 16 + cl;
    for (int j = 0; j < 8; j++){
      int k = ks * 32 + kg * 8 + j;
      float val = W1[(size_t)k * 640 + col];
      unsigned short hu = f2b_rne(val);
      float lof = val - us2f(hu);
      Bp3[((size_t)(ks * 40) + f) * 512 + lane * 8 + j]       = (short)hu;
      Bp3[((size_t)((2 + ks) * 40) + f) * 512 + lane * 8 + j] = (short)f2b_rne(lof);
    }
  } else {
    int ks = b - 226;
    for (int j = 0; j < 8; j++){
      int k = ks * 32 + kg * 8 + j;
      float val = (cl < 10) ? W2[k * 10 + cl] : 0.f;
      unsigned short hu = f2b_rne(val);
      Bp4[((size_t)ks) * 512 + lane * 8 + j]        = (short)hu;
      Bp4[((size_t)(20 + ks)) * 512 + lane * 8 + j] = (short)f2b_rne(val - us2f(hu));
    }
  }
}

// ---------- prep_x: xb = bf16(x) + alpha1 GEMM + fused edge-count (grid-stride) ----------
__global__ void __launch_bounds__(256)
k_prep_x(const float* __restrict__ x, const short* __restrict__ Bp1,
         const int* __restrict__ row, int* __restrict__ cnt, int E,
         short* __restrict__ xb, float* __restrict__ a1s, float* __restrict__ a1d,
         int n_nodes){
  __shared__ short xsh[16][72];   // hi bf16
  __shared__ short xsl[16][72];   // lo bf16
  int n0 = blockIdx.x * 16;
  int t = threadIdx.x;
  // ---- fused k_count: grid covers E (grid-stride for safety) ----
  for (int e = blockIdx.x * 256 + t; e < E; e += gridDim.x * 256)
    atomicAdd(&cnt[row[e]], 1);
  for (int i = t; i < 16 * 64; i += 256){
    int r = i >> 6, c = i & 63;
    int nn = n0 + r;
    float v = (nn < n_nodes) ? x[(size_t)nn * NF + c] : 0.f;
    unsigned short hu = f2b_rne(v);
    float lof = v - us2f(hu);
    xsh[r][c] = (short)hu;
    xsl[r][c] = (short)f2b_rne(lof);
  }
  __syncthreads();
  // coalesced xb write (hi bf16 only: gather payload)
  for (int i = t; i < 16 * 8; i += 256){
    int r = i >> 3, c8 = (i & 7) * 8;
    int nn = n0 + r;
    if (nn < n_nodes)
      *reinterpret_cast<short8*>(xb + (size_t)nn * 64 + c8) =
        *reinterpret_cast<const short8*>(&xsh[r][c8]);
  }
  int wid = t >> 6, lane = t & 63;
  if (wid == 3){                       // alpha frag (f=32): 16 alpha cols
    int rowa = lane & 15, kg = lane >> 4, cl = lane & 15;
    short8 ah[2], al[2];
    #pragma unroll
    for (int ks = 0; ks < 2; ks++){
      ah[ks] = *reinterpret_cast<const short8*>(&xsh[rowa][ks * 32 + kg * 8]);
      al[ks] = *reinterpret_cast<const short8*>(&xsl[rowa][ks * 32 + kg * 8]);
    }
    f32x4 acc = {0.f, 0.f, 0.f, 0.f};
    #pragma unroll
    for (int ks = 0; ks < 2; ks++){
      short8 b_h = *reinterpret_cast<const short8*>(Bp1 + ((size_t)(ks * 33) + 32) * 512 + lane * 8);
      short8 b_l = *reinterpret_cast<const short8*>(Bp1 + ((size_t)((2 + ks) * 33) + 32) * 512 + lane * 8);
      acc = mfma16(ah[ks], b_h, acc);
      acc = mfma16(al[ks], b_h, acc);
      acc = mfma16(ah[ks], b_l, acc);
    }
    #pragma unroll
    for (int reg = 0; reg < 4; reg++){
      int nn = n0 + kg * 4 + reg;
      if (nn < n_nodes){
        if (cl < 8) a1s[nn * NH + cl] = acc[reg];
        else        a1d[nn * NH + (cl - 8)] = acc[reg];
      }
    }
  }
}

// ---------- single-pass CSR offsets: block scan + atomic base (order-free ranges) ----------
// rowptr[i] need not be monotone in i: any disjoint per-node ranges of size cnt[i] are
// correct, since all consumers index scol exclusively through rowptr[n].
__global__ void k_scan(const int* __restrict__ cnt, int* __restrict__ gtot,
                       int* __restrict__ rowptr, int* __restrict__ wptr, int n){
  __shared__ int s[1024];
  __shared__ int base;
  int i = blockIdx.x * 1024 + threadIdx.x;
  int v = (i < n) ? cnt[i] : 0;
  s[threadIdx.x] = v;
  __syncthreads();
  for (int d = 1; d < 1024; d <<= 1){
    int tv = (threadIdx.x >= d) ? s[threadIdx.x - d] : 0;
    __syncthreads();
    s[threadIdx.x] += tv;
    __syncthreads();
  }
  if (threadIdx.x == 1023) base = atomicAdd(gtot, s[1023]);
  __syncthreads();
  if (i < n){
    int start = base + s[threadIdx.x] - v;
    rowptr[i] = start;
    wptr[i]   = start;
  }
}

__global__ void k_scatter(const int* __restrict__ row, const int* __restrict__ col,
                          int* __restrict__ wptr, int* __restrict__ scol, int E){
  int e = blockIdx.x * blockDim.x + threadIdx.x;
  if (e < E){
    int r = row[e];
    int pos = atomicAdd(&wptr[r], 1);
    scol[pos] = col[e];
  }
}

// ---------- fused agg1 (MFMA edge aggregation, LDS-staged A) + per-head W + Wout MFMA ----------
// 8 nodes/block, 512 threads (8 waves), 1 node/wave. (Best-known config.)
__global__ void __launch_bounds__(512, 2)
k_agg1_gemm2(const short* __restrict__ xb, const float* __restrict__ a1s,
             const float* __restrict__ a1d, const int* __restrict__ rowptr,
             const int* __restrict__ cnt, const int* __restrict__ scol,
             const short* __restrict__ Bp1, const short* __restrict__ Bp2,
             bf16* __restrict__ h2b, float* __restrict__ a2s,
             float* __restrict__ a2d, int n_nodes){
  __shared__ short Xs[8][2184];  // per-wave 32-row staging, stride 68 shorts
  __shared__ short Gh[8 * 600];  // [node][h*72 + feat] bf16
  __shared__ short xh[8][528];   // elu(h') bf16
  int n0   = blockIdx.x * 8;
  int wid  = threadIdx.x >> 6;
  int lane = threadIdx.x & 63;
  int kg = lane >> 4, cl = lane & 15;
  int hsel = lane & 7;
  int n = n0 + wid;

  if (n < n_nodes){
    int beg = rowptr[n], deg = cnt[n];
    float asrc = a1s[n * NH + hsel];
    short* xsw = &Xs[wid][0];
    int srow = lane >> 3, sseg = lane & 7;   // staging role: 8 rows x 8 segs per iter
    f32x4 accD[4];
    #pragma unroll
    for (int fb = 0; fb < 4; fb++){ accD[fb][0]=0.f; accD[fb][1]=0.f; accD[fb][2]=0.f; accD[fb][3]=0.f; }
    float rsum_part = 0.f;
    for (int p = 0; p < deg; p += 32){
      // ---- stage 32 edge rows into LDS (coalesced 16B/lane) ----
      #pragma unroll
      for (int it = 0; it < 4; it++){
        int row = it * 8 + srow;
        int kk = p + row;
        int cr = scol[beg + ((kk < deg) ? kk : 0)];
        short8 v = *reinterpret_cast<const short8*>(xb + (size_t)cr * 64 + sseg * 8);
        *reinterpret_cast<short8*>(&xsw[row * 68 + sseg * 8]) = v;
      }
      // ---- e-weights (kg group covers edges kg*8..kg*8+7, head hsel) ----
      int c[8];
      #pragma unroll
      for (int j = 0; j < 8; j++){
        int kk = p + kg * 8 + j;
        c[j] = scol[beg + ((kk < deg) ? kk : 0)];
      }
      float ef[8];
      #pragma unroll
      for (int j = 0; j < 8; j++){
        float s = asrc + a1d[c[j] * NH + hsel];
        float l = fmaxf(s, SLOPE * s);
        float e = __expf(-l);
        ef[j] = ((p + kg * 8 + j) < deg) ? e : 0.f;
        rsum_part += ef[j];
      }
      short8 bfrag;
      #pragma unroll
      for (int j = 0; j < 8; j++) bfrag[j] = (short)f2b_rne(ef[j]);
      // ---- A-fragments from LDS; 4 MFMAs ----
      #pragma unroll
      for (int fb = 0; fb < 4; fb++){
        short8 afrag;
        #pragma unroll
        for (int j = 0; j < 8; j++)
          afrag[j] = xsw[(kg * 8 + j) * 68 + fb * 16 + cl];
        accD[fb] = mfma16(afrag, bfrag, accD[fb]);
      }
    }
    // rsum for head hsel: reduce partials across the 4 kg groups
    float rsum = rsum_part;
    rsum += __shfl_xor(rsum, 16);
    rsum += __shfl_xor(rsum, 32);
    float inv = 1.f / rsum;
    if (cl < 8){
      #pragma unroll
      for (int fb = 0; fb < 4; fb++){
        #pragma unroll
        for (int reg = 0; reg < 4; reg++)
          Gh[wid * 600 + cl * 72 + fb * 16 + kg * 4 + reg] =
            (short)f2b_rne(accD[fb][reg] * inv);
      }
    }
  } else {
    if (cl < 8){
      #pragma unroll
      for (int fb = 0; fb < 4; fb++){
        #pragma unroll
        for (int reg = 0; reg < 4; reg++)
          Gh[wid * 600 + cl * 72 + fb * 16 + kg * 4 + reg] = 0;
      }
    }
  }
  __syncthreads();

  // ---- phase 2a: per-head W GEMM; wave w = head w; ELU epilogue -> xh ----
  {
    int rowa = lane & 7;            // A rows 8-15 duplicate 0-7 (outputs discarded)
    short8 gah[2];
    #pragma unroll
    for (int ks = 0; ks < 2; ks++)
      gah[ks] = *reinterpret_cast<const short8*>(&Gh[rowa * 600 + wid * 72 + ks * 32 + kg * 8]);
    #pragma unroll
    for (int fc = 0; fc < 4; fc++){
      int f = wid * 4 + fc;
      f32x4 acc = {0.f, 0.f, 0.f, 0.f};
      #pragma unroll
      for (int ks = 0; ks < 2; ks++){
        short8 b_h = *reinterpret_cast<const short8*>(Bp1 + ((size_t)(ks * 33) + f) * 512 + lane * 8);
        short8 b_l = *reinterpret_cast<const short8*>(Bp1 + ((size_t)((2 + ks) * 33) + f) * 512 + lane * 8);
        acc = mfma16(gah[ks], b_h, acc);
        acc = mfma16(gah[ks], b_l, acc);
      }
      if (kg < 2){                  // D rows 0-7 = the 8 nodes
        #pragma unroll
        for (int reg = 0; reg < 4; reg++){
          int r = kg * 4 + reg;
          float v = acc[reg];
          v = (v > 0.f) ? v : (__expf(v) - 1.f);   // elu
          xh[r][wid * 64 + fc * 16 + cl] = (short)f2b_rne(v);
        }
      }
    }
  }
  __syncthreads();

  // ---- phase 2b: Wout MFMA; waves 0-3 -> h2b cols, wave 4 -> alpha2 ----
  if (wid < 5){
    int rowa = lane & 7;
    f32x4 acc = {0.f, 0.f, 0.f, 0.f};
    #pragma unroll 4
    for (int ks = 0; ks < 16; ks++){
      short8 a_h = *reinterpret_cast<const short8*>(&xh[rowa][ks * 32 + kg * 8]);
      short8 b_h = *reinterpret_cast<const short8*>(Bp2 + ((size_t)(ks * 5) + wid) * 512 + lane * 8);
      short8 b_l = *reinterpret_cast<const short8*>(Bp2 + ((size_t)((16 + ks) * 5) + wid) * 512 + lane * 8);
      acc = mfma16(a_h, b_h, acc);
      acc = mfma16(a_h, b_l, acc);
    }
    if (kg < 2){
      #pragma unroll
      for (int reg = 0; reg < 4; reg++){
        int nn = n0 + kg * 4 + reg;
        if (nn < n_nodes){
          if (wid < 4){
            h2b[(size_t)nn * 64 + wid * 16 + cl] = __float2bfloat16(acc[reg]);
          } else if (cl == 0){
            a2s[nn] = acc[reg];
          } else if (cl == 1){
            a2d[nn] = acc[reg];
          }
        }
      }
    }
  }
}

// ---------- aggregation layer 2: 8 nodes/wave, 8-lane groups, 2-edge unroll (best-known) ----------
__global__ void __launch_bounds__(256)
k_agg2(const bf16* __restrict__ h2b, const float* __restrict__ a2s,
       const float* __restrict__ a2d, const int* __restrict__ rowptr,
       const int* __restrict__ cnt, const int* __restrict__ scol,
       float* __restrict__ xo, int n_nodes){
  int wid  = threadIdx.x >> 6;
  int lane = threadIdx.x & 63;
  int g = lane >> 3, sl = lane & 7;
  int n = blockIdx.x * 32 + wid * 8 + g;
  bool nv = (n < n_nodes);
  int beg = 0, deg = 0;
  float asrc = 0.f;
  if (nv){ beg = rowptr[n]; deg = cnt[n]; asrc = a2s[n]; }
  int mdeg = deg;
  #pragma unroll
  for (int m = 8; m < 64; m <<= 1){
    int o = __shfl_xor(mdeg, m);
    mdeg = (o > mdeg) ? o : mdeg;
  }
  f32x2 acc2[4] = {{0.f,0.f},{0.f,0.f},{0.f,0.f},{0.f,0.f}};
  float rsum = 0.f;
  int it = 0;
  for (; it + 1 < mdeg; it += 2){
    int i0 = (it     < deg) ? it     : 0;
    int i1 = (it + 1 < deg) ? it + 1 : 0;
    int c0 = scol[beg + i0];
    int c1 = scol[beg + i1];
    uint4v h0 = *reinterpret_cast<const uint4v*>(h2b + ((size_t)c0 << 6) + sl * 8);
    uint4v h1 = *reinterpret_cast<const uint4v*>(h2b + ((size_t)c1 << 6) + sl * 8);
    float s0 = asrc + a2d[c0];
    float s1 = asrc + a2d[c1];
    float l0 = fmaxf(s0, SLOPE * s0);
    float l1 = fmaxf(s1, SLOPE * s1);
    float e0 = __expf(-l0);
    float e1 = __expf(-l1);
    e0 = (it     < deg) ? e0 : 0.f;
    e1 = (it + 1 < deg) ? e1 : 0.f;
    rsum += e0 + e1;
    f32x2 ev0 = {e0, e0}, ev1 = {e1, e1};
    #pragma unroll
    for (int d = 0; d < 4; d++){
      f32x2 hv0 = {lo16(h0[d]), hi16(h0[d])};
      f32x2 hv1 = {lo16(h1[d]), hi16(h1[d])};
      acc2[d] += ev0 * hv0 + ev1 * hv1;
    }
  }
  if (it < mdeg){
    int i0 = (it < deg) ? it : 0;
    int c0 = scol[beg + i0];
    uint4v h0 = *reinterpret_cast<const uint4v*>(h2b + ((size_t)c0 << 6) + sl * 8);
    float s0 = asrc + a2d[c0];
    float l0 = fmaxf(s0, SLOPE * s0);
    float e0 = __expf(-l0);
    e0 = (it < deg) ? e0 : 0.f;
    rsum += e0;
    f32x2 ev0 = {e0, e0};
    #pragma unroll
    for (int d = 0; d < 4; d++){
      f32x2 hv0 = {lo16(h0[d]), hi16(h0[d])};
      acc2[d] += ev0 * hv0;
    }
  }
  if (nv){
    float inv = 1.f / rsum;
    float4 lo, hi;
    float vv[8];
    #pragma unroll
    for (int jj = 0; jj < 8; jj++){
      float v = acc2[jj >> 1][jj & 1] * inv;
      vv[jj] = (v > 0.f) ? v : (__expf(v) - 1.f);   // elu after layer 2
    }
    lo.x = vv[0]; lo.y = vv[1]; lo.z = vv[2]; lo.w = vv[3];
    hi.x = vv[4]; hi.y = vv[5]; hi.z = vv[6]; hi.w = vv[7];
    *reinterpret_cast<float4*>(xo + (size_t)n * 64 + sl * 8)     = lo;
    *reinterpret_cast<float4*>(xo + (size_t)n * 64 + sl * 8 + 4) = hi;
  }
}

// ---------- MLP head: MFMA for W1 AND W2 stages, 16 nodes/block ----------
__global__ void __launch_bounds__(256)
k_mlp(const float* __restrict__ xo, const short* __restrict__ Bp3,
      const short* __restrict__ Bp4, const float* __restrict__ b1,
      const float* __restrict__ b2, const float* __restrict__ W3,
      const float* __restrict__ b3, float* __restrict__ out, int n_nodes){
  __shared__ short xsh[16][72];
  __shared__ short xsl[16][72];
  __shared__ short z1h[16][648];     // relu(xo@W1+b1) bf16
  __shared__ float part[4][16][16];  // split-K partials for z1@W2
  __shared__ float z2[16][10];
  int n0 = blockIdx.x * 16;
  int t  = threadIdx.x;
  for (int i = t; i < 16 * 64; i += 256){
    int r = i >> 6, c = i & 63;
    int nn = n0 + r;
    float v = (nn < n_nodes) ? xo[(size_t)nn * 64 + c] : 0.f;
    unsigned short hu = f2b_rne(v);
    float lof = v - us2f(hu);
    xsh[r][c] = (short)hu;
    xsl[r][c] = (short)f2b_rne(lof);
  }
  __syncthreads();
  int wid = t >> 6, lane = t & 63;
  int rowa = lane & 15, kg = lane >> 4, cl = lane & 15;
  // ---- stage B: z1 = relu(xo @ W1 + b1) via MFMA ----
  {
    short8 ah[2], al[2];
    #pragma unroll
    for (int ks = 0; ks < 2; ks++){
      ah[ks] = *reinterpret_cast<const short8*>(&xsh[rowa][ks * 32 + kg * 8]);
      al[ks] = *reinterpret_cast<const short8*>(&xsl[rowa][ks * 32 + kg * 8]);
    }
    for (int f0 = 0; f0 < 10; f0++){
      int f = wid * 10 + f0;
      f32x4 acc = {0.f, 0.f, 0.f, 0.f};
      #pragma unroll
      for (int ks = 0; ks < 2; ks++){
        short8 b_h = *reinterpret_cast<const short8*>(Bp3 + ((size_t)(ks * 40) + f) * 512 + lane * 8);
        short8 b_l = *reinterpret_cast<const short8*>(Bp3 + ((size_t)((2 + ks) * 40) + f) * 512 + lane * 8);
        acc = mfma16(ah[ks], b_h, acc);
        acc = mfma16(al[ks], b_h, acc);
        acc = mfma16(ah[ks], b_l, acc);
      }
      int cc = f * 16 + cl;
      float bb = b1[cc];
      #pragma unroll
      for (int reg = 0; reg < 4; reg++)
        z1h[kg * 4 + reg][cc] = (short)f2b_rne(fmaxf(acc[reg] + bb, 0.f));
    }
  }
  __syncthreads();
  // ---- stage C: z2 = relu(z1 @ W2 + b2) via MFMA, split-K over 4 waves ----
  {
    f32x4 acc = {0.f, 0.f, 0.f, 0.f};
    #pragma unroll
    for (int kk = 0; kk < 5; kk++){
      int ks = wid * 5 + kk;
      short8 a_h = *reinterpret_cast<const short8*>(&z1h[rowa][ks * 32 + kg * 8]);
      short8 b_h = *reinterpret_cast<const short8*>(Bp4 + ((size_t)ks) * 512 + lane * 8);
      short8 b_l = *reinterpret_cast<const short8*>(Bp4 + ((size_t)(20 + ks)) * 512 + lane * 8);
      acc = mfma16(a_h, b_h, acc);
      acc = mfma16(a_h, b_l, acc);
    }
    #pragma unroll
    for (int reg = 0; reg < 4; reg++)
      part[wid][kg * 4 + reg][cl] = acc[reg];
  }
  __syncthreads();
  if (t < 160){
    int r = t / 10, c = t % 10;
    float v = (part[0][r][c] + part[1][r][c]) + (part[2][r][c] + part[3][r][c]);
    z2[r][c] = fmaxf(v + b2[c], 0.f);
  }
  __syncthreads();
  // ---- stage D: sigmoid(z2 @ W3 + b3) ----
  if (t < 16){
    int nn = n0 + t;
    if (nn < n_nodes){
      float acc = b3[0];
      #pragma unroll
      for (int kk = 0; kk < 10; kk++) acc += z2[t][kk] * W3[kk];
      out[nn] = 1.f / (1.f + __expf(-acc));
    }
  }
}

extern "C" void kernel_launch(void* const* d_in, const int* in_sizes, int n_in,
                              void* d_out, int out_size, void* d_ws, size_t ws_size,
                              hipStream_t stream){
  const float* x    = (const float*)d_in[0];
  const int*   ei   = (const int*)  d_in[1];
  const float* Watt = (const float*)d_in[2];
  const float* aatt = (const float*)d_in[3];
  const float* Wout = (const float*)d_in[4];
  const float* aout = (const float*)d_in[5];
  const float* W1   = (const float*)d_in[6];
  const float* b1   = (const float*)d_in[7];
  const float* W2   = (const float*)d_in[8];
  const float* b2   = (const float*)d_in[9];
  const float* W3   = (const float*)d_in[10];
  const float* b3   = (const float*)d_in[11];
  float* out = (float*)d_out;

  int N = in_sizes[0] / NF;
  int E = in_sizes[1] / 2;
  const int* row = ei;
  const int* col = ei + E;

  char* base = (char*)d_ws;
  size_t off = 0;
  auto alloc = [&](size_t bytes) -> void* {
    void* p = base + off;
    off = (off + bytes + 255) & ~(size_t)255;
    return p;
  };
  short* xb     = (short*)alloc((size_t)N * 64 * 2);   // 12.8 MB bf16 x (L2-resident gather target)
  bf16*  h2b    = (bf16*) alloc((size_t)N * 64 * 2);   // 12.8 MB
  float* xo     = (float*)alloc((size_t)N * 64 * 4);   // 25.6 MB
  float* a1s    = (float*)alloc((size_t)N * NH * 4);
  float* a1d    = (float*)alloc((size_t)N * NH * 4);
  float* a2s    = (float*)alloc((size_t)N * 4);
  float* a2d    = (float*)alloc((size_t)N * 4);
  int*   cnt    = (int*)  alloc((size_t)N * 4);
  int*   rowptr = (int*)  alloc((size_t)N * 4);
  int*   wptr   = (int*)  alloc((size_t)N * 4);
  int*   gtot   = (int*)  alloc(4);
  int    NB     = (N + 1023) / 1024;
  int*   scol   = (int*)  alloc((size_t)E * 4);        // 6.4 MB
  short* Bp1    = (short*)alloc((size_t)4 * 33 * 512 * 2);   // 135 KB packed W_att|alpha1
  short* Bp2    = (short*)alloc((size_t)32 * 5 * 512 * 2);   // 160 KB packed Wout|alpha2
  short* Bp3    = (short*)alloc((size_t)4 * 40 * 512 * 2);   // 160 KB packed W1
  short* Bp4    = (short*)alloc((size_t)40 * 512 * 2);       // 40 KB packed W2
  (void)ws_size; (void)n_in; (void)out_size;

  hipMemsetAsync(cnt, 0, (size_t)N * 4, stream);

  k_prep_all  <<<246,             64, 0, stream>>>(Watt, aatt, Wout, aout, W1, W2,
                                                   Bp1, Bp2, Bp3, Bp4, gtot);
  k_prep_x    <<<(N + 15) / 16,  256, 0, stream>>>(x, Bp1, row, cnt, E, xb, a1s, a1d, N);
  k_scan      <<<NB,             1024, 0, stream>>>(cnt, gtot, rowptr, wptr, N);
  k_scatter   <<<(E + 255) / 256, 256, 0, stream>>>(row, col, wptr, scol, E);
  k_agg1_gemm2<<<(N + 7) / 8,     512, 0, stream>>>(xb, a1s, a1d, rowptr, cnt, scol,
                                                    Bp1, Bp2, h2b, a2s, a2d, N);
  k_agg2      <<<(N + 31) / 32,  256, 0, stream>>>(h2b, a2s, a2d, rowptr, cnt, scol, xo, N);
  k_mlp       <<<(N + 15) / 16,  256, 0, stream>>>(xo, Bp3, Bp4, b1, b2, W3, b3, out, N);
}